// Round 1
// baseline (39.458 us; speedup 1.0000x reference)
//
#include <hip/hip_runtime.h>

// LengthRegulator: out[b,t,:] = x[b, searchsorted(cum[b], t, 'right'), :] * (t < mel_len[b])
// Shapes: x (32, 256, 384) f32, duration (32, 256) int, max_len = 4096.
// Output: flat [32*4096*384] f32  ++  [32] mel_len (written as f32; harness
// reads the whole output buffer as float32 and slices per-output).

constexpr int B  = 32;
constexpr int S  = 256;
constexpr int D  = 384;
constexpr int ML = 4096;
constexpr int D4 = D / 4;     // 96 float4 per row
constexpr int ROWS = 16;      // output rows per expand block
constexpr int TB = 256;       // threads per block

// Per-batch inclusive scan of duration -> cum (ws), mel_len -> out tail.
__global__ __launch_bounds__(TB) void lr_scan_kernel(const int* __restrict__ dur,
                                                     int* __restrict__ cum,
                                                     float* __restrict__ mel_out) {
    const int b = blockIdx.x;
    const int tid = threadIdx.x;
    __shared__ int s[S];
    s[tid] = dur[b * S + tid];
    __syncthreads();
    // Hillis-Steele inclusive scan over S=256 elements
    for (int off = 1; off < S; off <<= 1) {
        int v = (tid >= off) ? s[tid - off] : 0;
        __syncthreads();
        s[tid] += v;
        __syncthreads();
    }
    cum[b * S + tid] = s[tid];
    if (tid == S - 1) mel_out[b] = (float)s[tid];
}

// Expansion: one block = one batch x ROWS output rows. Gather float4 rows.
__global__ __launch_bounds__(TB) void lr_expand_kernel(const float4* __restrict__ x,
                                                       const int* __restrict__ cum,
                                                       float4* __restrict__ out) {
    constexpr int RPB = ML / ROWS;          // row-blocks per batch = 256
    const int b      = blockIdx.x / RPB;
    const int rowblk = blockIdx.x % RPB;
    const int tid    = threadIdx.x;

    __shared__ int scum[S];
    __shared__ int sidx[ROWS];
    scum[tid] = cum[b * S + tid];
    __syncthreads();
    const int mel = scum[S - 1];

    // One binary search per output row: first index j with scum[j] > t,
    // clipped to S-1 (searchsorted side='right' + clip).
    if (tid < ROWS) {
        const int t = rowblk * ROWS + tid;
        int lo = 0, hi = S;
        while (lo < hi) {
            int mid = (lo + hi) >> 1;
            if (scum[mid] <= t) lo = mid + 1; else hi = mid;
        }
        sidx[tid] = (lo < S) ? lo : (S - 1);
    }
    __syncthreads();

    const float4* xb = x + (size_t)b * S * D4;
    float4* ob = out + ((size_t)b * ML + (size_t)rowblk * ROWS) * D4;

    // ROWS*D4 = 1536 float4 per block; flat index j is store-contiguous.
    for (int j = tid; j < ROWS * D4; j += TB) {
        const int tl = j / D4;
        const int d4 = j - tl * D4;
        const int t  = rowblk * ROWS + tl;
        float4 v;
        if (t < mel) {
            v = xb[(size_t)sidx[tl] * D4 + d4];
        } else {
            v = make_float4(0.f, 0.f, 0.f, 0.f);
        }
        ob[j] = v;
    }
}

extern "C" void kernel_launch(void* const* d_in, const int* in_sizes, int n_in,
                              void* d_out, int out_size, void* d_ws, size_t ws_size,
                              hipStream_t stream) {
    const float* x   = (const float*)d_in[0];
    const int*   dur = (const int*)d_in[1];
    float* out = (float*)d_out;
    int*   cum = (int*)d_ws;                              // B*S ints = 32 KB
    float* mel_out = out + (size_t)B * ML * D;            // output 1 tail

    lr_scan_kernel<<<B, TB, 0, stream>>>(dur, cum, mel_out);
    lr_expand_kernel<<<B * (ML / ROWS), TB, 0, stream>>>(
        (const float4*)x, cum, (float4*)out);
}